// Round 8
// baseline (153.593 us; speedup 1.0000x reference)
//
#include <hip/hip_runtime.h>
#include <hip/hip_bf16.h>

// ============ INSTRUMENTATION ROUND: gemm body runs rep=3x (idempotent) ====
// Purpose: lift gemm_mfma above the ~120us harness fills so its counters
// appear in the top-5. Revert REPS to 1 next round.
#define REPS 3

#define BS    256
#define PIX   1024
#define CBAND 200
#define NK    7            // K-steps of 32 (K 200 -> 224; tail k>=200 hits B=0)
#define FEAT  64
#define ALPHA 0.2f
#define BETA  0.5f
#define TROWS 32           // rows per K-tile
#define TBYTES (TROWS * CBAND * 4)   // 25600 B = 25 x 1KB wave-chunks
#define NTILE 4            // tiles per block (128 rows/block, grid 2048)
#define SLACK 128          // LDS slack so ks=6 tail reads stay in-bounds (zeroed)

typedef __attribute__((ext_vector_type(8))) short bf16x8;   // MFMA A/B fragment
typedef __attribute__((ext_vector_type(4))) float f32x4;    // MFMA C/D fragment

__device__ __forceinline__ float lrelu(float v) { return v >= 0.f ? v : ALPHA * v; }
__device__ __forceinline__ float bf2f(short s) {
    unsigned int u = ((unsigned int)(unsigned short)s) << 16;
    return __uint_as_float(u);
}
__device__ __forceinline__ unsigned int pkbf(float a, float b) {
    __hip_bfloat162 t = __float22bfloat162_rn(make_float2(a, b));
    return *(unsigned int*)&t;
}
// async global->LDS, 16B per lane; LDS dest = uniform base + lane*16
__device__ __forceinline__ void load_lds16(const void* g, void* l) {
    __builtin_amdgcn_global_load_lds(
        (const __attribute__((address_space(1))) void*)g,
        (__attribute__((address_space(3))) void*)l, 16, 0, 0);
}

// ---------------------------------------------------------------------------
// Kernel 0 (fused prep), 256 threads/block.
// Blocks 0..13: pack Wk||Wv into bf16 B-fragments.
// Blocks 14..269: central-pixel features (fp32 exact), K split 4 ways.
// ---------------------------------------------------------------------------
__global__ __launch_bounds__(256) void prep_k(
    const float* __restrict__ x, const float* __restrict__ Wk,
    const float* __restrict__ Wv, const float* __restrict__ Wn,
    unsigned short* __restrict__ Wb, float* __restrict__ c1,
    float* __restrict__ chalf)
{
    const int tid = threadIdx.x;
    if (blockIdx.x < 14) {
        int bid2 = blockIdx.x * 4 + (tid >> 6);   // 0..55
        int l  = tid & 63;
        int nf = bid2 & 7;
        int ks = bid2 >> 3;
        int c  = nf * 16 + (l & 15);
        int k0 = ks * 32 + (l >> 4) * 8;
        __attribute__((aligned(16))) unsigned short o[8];
        #pragma unroll
        for (int i = 0; i < 8; ++i) {
            int k = k0 + i;
            float w = 0.f;
            if (k < CBAND) w = (c < 64) ? Wk[k * 64 + c] : Wv[k * 64 + (c - 64)];
            unsigned int u = __float_as_uint(w);
            u += 0x7FFFu + ((u >> 16) & 1u);      // RNE to bf16
            o[i] = (unsigned short)(u >> 16);
        }
        *(uint4*)&Wb[((size_t)bid2 * 64 + l) * 8] = *(uint4*)o;
        return;
    }
    __shared__ float xr[CBAND];
    __shared__ float part[2][4][FEAT];
    __shared__ float c2s[FEAT];
    int b = blockIdx.x - 14;
    int f = tid & 63, q = tid >> 6;
    const float* xc = x + (size_t)b * (PIX * CBAND) + (16 * 32 + 16) * CBAND;
    for (int c = tid; c < CBAND; c += 256) xr[c] = xc[c];
    __syncthreads();
    float a1 = 0.f, a2 = 0.f;
    #pragma unroll 5
    for (int c = q * 50; c < q * 50 + 50; ++c) {
        float xv = xr[c];
        a1 += xv * Wk[c * FEAT + f];
        a2 += xv * Wv[c * FEAT + f];
    }
    part[0][q][f] = a1;
    part[1][q][f] = a2;
    __syncthreads();
    if (tid < FEAT) {
        float s1 = part[0][0][f] + part[0][1][f] + part[0][2][f] + part[0][3][f];
        float s2 = part[1][0][f] + part[1][1][f] + part[1][2][f] + part[1][3][f];
        c1[b * FEAT + f] = lrelu(s1);
        c2s[f] = lrelu(s2);
    }
    __syncthreads();
    if (tid < FEAT) {
        float a3 = 0.f;
        #pragma unroll 8
        for (int g = 0; g < FEAT; ++g) a3 += c2s[g] * Wn[f * FEAT + g];
        chalf[b * FEAT + f] = BETA * lrelu(a3);
    }
}

// ---------------------------------------------------------------------------
// Kernel 1: MFMA GEMM, DMA-staged + double-buffered (R5 structure, REPS=3
// for counter visibility; every rep rewrites identical outputs).
// ---------------------------------------------------------------------------
__global__ __launch_bounds__(256) void gemm_mfma(
    const float* __restrict__ x, const unsigned short* __restrict__ Wb,
    const float* __restrict__ c1, float* __restrict__ mcT,
    unsigned short* __restrict__ h2)
{
    __shared__ __align__(16) float xbuf[2][(TBYTES + SLACK) / 4];
    __shared__ float c1s[FEAT];
    __shared__ float hpart[2][2][TROWS];

    const int tid = threadIdx.x;
    const int l   = tid & 63;
    const int w   = tid >> 6;
    const int bb  = blockIdx.x >> 3;              // 8 blocks per batch
    const int pbase = (blockIdx.x & 7) * (TROWS * NTILE);
    const size_t row0 = (size_t)blockIdx.x * (TROWS * NTILE);

    // zero the tail slack once (NaN-proof the ks=6 garbage reads)
    if (tid < SLACK / 4) {
        xbuf[0][TBYTES / 4 + tid] = 0.f;
        xbuf[1][TBYTES / 4 + tid] = 0.f;
    }
    if (tid < FEAT) c1s[tid] = c1[bb * FEAT + tid];

    // resident B fragments: wave w covers nf0=2w, nf0+1 for all 7 ks
    const bf16x8* wbv = (const bf16x8*)Wb;
    const int nf0 = 2 * w;
    bf16x8 bq[NK][2];
    #pragma unroll
    for (int ks = 0; ks < NK; ++ks)
        #pragma unroll
        for (int nj = 0; nj < 2; ++nj)
            bq[ks][nj] = wbv[(ks * 8 + nf0 + nj) * 64 + l];

    const char* xbase = (const char*)(x + row0 * CBAND);
    auto stage = [&](int t, int buf) {
        const char* g  = xbase + (size_t)t * TBYTES + l * 16;
        char*       lp = (char*)&xbuf[buf][0];
        for (int c = w; c < 25; c += 4)           // 25 x 1KB linear chunks
            load_lds16(g + c * 1024, lp + c * 1024);
    };

    const int fr = l & 15;     // fragment row / D col
    const int g4 = l >> 4;     // k subgroup / D row group

    for (int rep = 0; rep < REPS; ++rep) {
        stage(0, 0);

        for (int t = 0; t < NTILE; ++t) {
            __syncthreads();                      // drains vmcnt: stage(t) done
            if (t + 1 < NTILE) stage(t + 1, (t + 1) & 1);

            // combine previous tile's h1 partials
            if (t > 0 && w == 3 && l < TROWS) {
                int p = pbase + (t - 1) * TROWS + l;
                float v = (hpart[(t - 1) & 1][0][l] + hpart[(t - 1) & 1][1][l]) * (1.f / 64.f);
                mcT[(size_t)p * BS + bb] = v;
            }

            const float* xb = &xbuf[t & 1][0];
            f32x4 acc[2][2];
            #pragma unroll
            for (int mi = 0; mi < 2; ++mi)
                #pragma unroll
                for (int nj = 0; nj < 2; ++nj) acc[mi][nj] = (f32x4){0.f, 0.f, 0.f, 0.f};

            #pragma unroll
            for (int ks = 0; ks < NK; ++ks) {
                bf16x8 a[2];
                #pragma unroll
                for (int mi = 0; mi < 2; ++mi) {
                    int r = mi * 16 + fr;
                    const float* src = xb + r * CBAND + ks * 32 + g4 * 8;
                    f32x4 lo = *(const f32x4*)src;
                    f32x4 hi = *(const f32x4*)(src + 4);
                    union { bf16x8 v; unsigned int u[4]; } af;
                    af.u[0] = pkbf(lo[0], lo[1]);
                    af.u[1] = pkbf(lo[2], lo[3]);
                    af.u[2] = pkbf(hi[0], hi[1]);
                    af.u[3] = pkbf(hi[2], hi[3]);
                    a[mi] = af.v;
                }
                #pragma unroll
                for (int nj = 0; nj < 2; ++nj) {
                    acc[0][nj] = __builtin_amdgcn_mfma_f32_16x16x32_bf16(a[0], bq[ks][nj], acc[0][nj], 0, 0, 0);
                    acc[1][nj] = __builtin_amdgcn_mfma_f32_16x16x32_bf16(a[1], bq[ks][nj], acc[1][nj], 0, 0, 0);
                }
            }

            if (w < 2) {
                // h1 waves: partial f-dot with c1, reduce over 16 cols in-wave
                #pragma unroll
                for (int mi = 0; mi < 2; ++mi) {
                    #pragma unroll
                    for (int r = 0; r < 4; ++r) {
                        float part = 0.f;
                        #pragma unroll
                        for (int nj = 0; nj < 2; ++nj)
                            part += lrelu(acc[mi][nj][r]) * c1s[(nf0 + nj) * 16 + fr];
                        part += __shfl_xor(part, 1);
                        part += __shfl_xor(part, 2);
                        part += __shfl_xor(part, 4);
                        part += __shfl_xor(part, 8);
                        if (fr == 0) hpart[t & 1][w][mi * 16 + g4 * 4 + r] = part;
                    }
                }
            } else {
                // h2 waves: store lrelu as bf16, layout h2[b][f][p], 4 p/lane
                #pragma unroll
                for (int mi = 0; mi < 2; ++mi) {
                    int p0 = pbase + t * TROWS + mi * 16 + g4 * 4;
                    #pragma unroll
                    for (int nj = 0; nj < 2; ++nj) {
                        int f = (nf0 + nj - 4) * 16 + fr;
                        uint2 pk;
                        pk.x = pkbf(lrelu(acc[mi][nj][0]), lrelu(acc[mi][nj][1]));
                        pk.y = pkbf(lrelu(acc[mi][nj][2]), lrelu(acc[mi][nj][3]));
                        *(uint2*)&h2[(((size_t)bb * 64 + f) << 10) + p0] = pk;
                    }
                }
            }
        }
        __syncthreads();
        if (w == 3 && l < TROWS) {                // final tile's h1 combine
            int p = pbase + (NTILE - 1) * TROWS + l;
            float v = (hpart[(NTILE - 1) & 1][0][l] + hpart[(NTILE - 1) & 1][1][l]) * (1.f / 64.f);
            mcT[(size_t)p * BS + bb] = v;
        }
        __syncthreads();                          // isolate reps
    }
}

// ---------------------------------------------------------------------------
// Kernel 2: softmax over batch per pixel; mcT[p][b] -> attnN[b][p]
// ---------------------------------------------------------------------------
__global__ __launch_bounds__(256) void softmax_b(
    const float* __restrict__ mcT, float* __restrict__ attnN)
{
    int p = blockIdx.x, t = threadIdx.x;
    float v = mcT[(size_t)p * BS + t];
    float m = v;
    #pragma unroll
    for (int o = 32; o > 0; o >>= 1) m = fmaxf(m, __shfl_xor(m, o));
    __shared__ float r1[4], r2[4];
    int w = t >> 6, lz = t & 63;
    if (lz == 0) r1[w] = m;
    __syncthreads();
    m = fmaxf(fmaxf(r1[0], r1[1]), fmaxf(r1[2], r1[3]));
    float e = expf(v - m);
    float s = e;
    #pragma unroll
    for (int o = 32; o > 0; o >>= 1) s += __shfl_xor(s, o);
    if (lz == 0) r2[w] = s;
    __syncthreads();
    s = r2[0] + r2[1] + r2[2] + r2[3];
    attnN[(size_t)t * PIX + p] = e / s;
}

// ---------------------------------------------------------------------------
// Kernel 3: neighbour[b,f] = sum_p h2[b][f][p] * attn[b][p]; blend w/ chalf.
// 1024 threads (16 waves) per block; wave handles 4 f values.
// ---------------------------------------------------------------------------
__global__ __launch_bounds__(1024) void neighbour_k(
    const unsigned short* __restrict__ h2, const float* __restrict__ attnN,
    const float* __restrict__ chalf, float* __restrict__ out)
{
    int b = blockIdx.x, tid = threadIdx.x;
    int l = tid & 63, w = tid >> 6;       // 16 waves
    __shared__ float att[PIX];
    if (tid < PIX) att[tid] = attnN[(size_t)b * PIX + tid];
    __syncthreads();

    float av[16];
    #pragma unroll
    for (int i = 0; i < 8; ++i) av[i]     = att[l * 8 + i];
    #pragma unroll
    for (int i = 0; i < 8; ++i) av[8 + i] = att[512 + l * 8 + i];

    const unsigned short* hb = h2 + ((size_t)b * 64) * 1024;
    #pragma unroll
    for (int j = 0; j < 4; ++j) {
        int f = w * 4 + j;
        const unsigned short* hf = hb + (size_t)f * 1024;
        bf16x8 h0 = *(const bf16x8*)&hf[l * 8];
        bf16x8 h1 = *(const bf16x8*)&hf[512 + l * 8];
        float acc = 0.f;
        #pragma unroll
        for (int i = 0; i < 8; ++i) acc += bf2f(h0[i]) * av[i];
        #pragma unroll
        for (int i = 0; i < 8; ++i) acc += bf2f(h1[i]) * av[8 + i];
        #pragma unroll
        for (int o = 32; o > 0; o >>= 1) acc += __shfl_xor(acc, o);
        if (l == 0)
            out[b * FEAT + f] = chalf[b * FEAT + f] + (1.f - BETA) * acc;
    }
}

// ---------------------------------------------------------------------------
extern "C" void kernel_launch(void* const* d_in, const int* in_sizes, int n_in,
                              void* d_out, int out_size, void* d_ws, size_t ws_size,
                              hipStream_t stream)
{
    const float* x  = (const float*)d_in[0];
    const float* Wk = (const float*)d_in[1];
    const float* Wv = (const float*)d_in[2];
    const float* Wn = (const float*)d_in[3];
    float* out = (float*)d_out;

    float* ws    = (float*)d_ws;
    float* c1    = ws;                                   // 16384 f
    float* chalf = ws + 16384;                           // 16384 f
    float* mcT   = ws + 32768;                           // 262144 f  [p][b]
    float* attnN = ws + 294912;                          // 262144 f  [b][p]
    unsigned short* Wb = (unsigned short*)(ws + 557056); // 28672 u16
    unsigned short* h2 = (unsigned short*)((char*)d_ws + 2285568); // 33.5 MB

    prep_k   <<<270,  256, 0, stream>>>(x, Wk, Wv, Wn, Wb, c1, chalf);
    gemm_mfma<<<2048, 256, 0, stream>>>(x, Wb, c1, mcT, h2);
    softmax_b<<<PIX,  256, 0, stream>>>(mcT, attnN);
    neighbour_k<<<BS, 1024, 0, stream>>>(h2, attnN, chalf, out);
}

// Round 9
// 69.879 us; speedup vs baseline: 2.1980x; 2.1980x over previous
//
#include <hip/hip_runtime.h>
#include <hip/hip_bf16.h>

#define BS    256
#define PIX   1024
#define CBAND 200
#define NK    7            // K-steps of 32 (K 200 -> 224; tail k>=200 hits B=0)
#define FEAT  64
#define ALPHA 0.2f
#define BETA  0.5f
#define TROWS 32           // rows per K-tile
#define NTILE 4            // tiles per block (128 rows/block, grid 2048)
#define XSTR  232          // LDS row stride in bf16 (464 B = 20 dwords mod 32 -> conflict-free b128)

typedef __attribute__((ext_vector_type(8))) short bf16x8;   // MFMA A/B fragment
typedef __attribute__((ext_vector_type(4))) float f32x4;    // MFMA C/D fragment

__device__ __forceinline__ float lrelu(float v) { return v >= 0.f ? v : ALPHA * v; }
__device__ __forceinline__ float bf2f(short s) {
    unsigned int u = ((unsigned int)(unsigned short)s) << 16;
    return __uint_as_float(u);
}
__device__ __forceinline__ unsigned int pkbf(float a, float b) {
    __hip_bfloat162 t = __float22bfloat162_rn(make_float2(a, b));
    return *(unsigned int*)&t;
}

// ---------------------------------------------------------------------------
// Kernel 0 (fused prep), 256 threads/block.
// Blocks 0..13: pack Wk||Wv into bf16 B-fragments.
// Blocks 14..269: central-pixel features (fp32 exact), K split 4 ways.
// ---------------------------------------------------------------------------
__global__ __launch_bounds__(256) void prep_k(
    const float* __restrict__ x, const float* __restrict__ Wk,
    const float* __restrict__ Wv, const float* __restrict__ Wn,
    unsigned short* __restrict__ Wb, float* __restrict__ c1,
    float* __restrict__ chalf)
{
    const int tid = threadIdx.x;
    if (blockIdx.x < 14) {
        int bid2 = blockIdx.x * 4 + (tid >> 6);   // 0..55
        int l  = tid & 63;
        int nf = bid2 & 7;
        int ks = bid2 >> 3;
        int c  = nf * 16 + (l & 15);
        int k0 = ks * 32 + (l >> 4) * 8;
        __attribute__((aligned(16))) unsigned short o[8];
        #pragma unroll
        for (int i = 0; i < 8; ++i) {
            int k = k0 + i;
            float w = 0.f;
            if (k < CBAND) w = (c < 64) ? Wk[k * 64 + c] : Wv[k * 64 + (c - 64)];
            unsigned int u = __float_as_uint(w);
            u += 0x7FFFu + ((u >> 16) & 1u);      // RNE to bf16
            o[i] = (unsigned short)(u >> 16);
        }
        *(uint4*)&Wb[((size_t)bid2 * 64 + l) * 8] = *(uint4*)o;
        return;
    }
    __shared__ float xr[CBAND];
    __shared__ float part[2][4][FEAT];
    __shared__ float c2s[FEAT];
    int b = blockIdx.x - 14;
    int f = tid & 63, q = tid >> 6;
    const float* xc = x + (size_t)b * (PIX * CBAND) + (16 * 32 + 16) * CBAND;
    for (int c = tid; c < CBAND; c += 256) xr[c] = xc[c];
    __syncthreads();
    float a1 = 0.f, a2 = 0.f;
    #pragma unroll 5
    for (int c = q * 50; c < q * 50 + 50; ++c) {
        float xv = xr[c];
        a1 += xv * Wk[c * FEAT + f];
        a2 += xv * Wv[c * FEAT + f];
    }
    part[0][q][f] = a1;
    part[1][q][f] = a2;
    __syncthreads();
    if (tid < FEAT) {
        float s1 = part[0][0][f] + part[0][1][f] + part[0][2][f] + part[0][3][f];
        float s2 = part[1][0][f] + part[1][1][f] + part[1][2][f] + part[1][3][f];
        c1[b * FEAT + f] = lrelu(s1);
        c2s[f] = lrelu(s2);
    }
    __syncthreads();
    if (tid < FEAT) {
        float a3 = 0.f;
        #pragma unroll 8
        for (int g = 0; g < FEAT; ++g) a3 += c2s[g] * Wn[f * FEAT + g];
        chalf[b * FEAT + f] = BETA * lrelu(a3);
    }
}

// ---------------------------------------------------------------------------
// Kernel 1: MFMA GEMM, reg-staged (T14 split) + padded bf16 LDS (conflict-free).
// Block: 4 tiles x 32 rows, 4 waves. Wave w -> N-frags {2w,2w+1}
// (w0,w1 = h1 cols 0..63; w2,w3 = h2 cols 64..127), all 32 rows per tile.
// Per tile-unit (800 units of 8 floats): load 2xfloat4 -> cvt bf16 -> one
// ds_write_b128 into xs[row][c8*8] with XSTR=232 (uniform bank coverage).
// A-read: bf16x8 at row*232 + ks*32 + g4*8 -> 8 bank-starts, conflict-free.
// Loads for tile t+2 issued in iter t (latency hidden under a full tile).
// ---------------------------------------------------------------------------
__global__ __launch_bounds__(256) void gemm_mfma(
    const float* __restrict__ x, const unsigned short* __restrict__ Wb,
    const float* __restrict__ c1, float* __restrict__ mcT,
    unsigned short* __restrict__ h2)
{
    __shared__ unsigned short xs[2][TROWS * XSTR];   // 2 x 14848 B
    __shared__ float c1s[FEAT];
    __shared__ float hpart[2][2][TROWS];

    const int tid = threadIdx.x;
    const int l   = tid & 63;
    const int w   = tid >> 6;
    const int bb  = blockIdx.x >> 3;              // 8 blocks per batch
    const int pbase = (blockIdx.x & 7) * (TROWS * NTILE);
    const size_t row0 = (size_t)blockIdx.x * (TROWS * NTILE);

    // zero the k-tail [200,232) of both buffers (ks=6 reads hit zeros)
    if (tid < 128) {
        int r = tid >> 2, q = tid & 3;
        *(uint4*)&xs[0][r * XSTR + 200 + q * 8] = make_uint4(0, 0, 0, 0);
        *(uint4*)&xs[1][r * XSTR + 200 + q * 8] = make_uint4(0, 0, 0, 0);
    }
    if (tid < FEAT) c1s[tid] = c1[bb * FEAT + tid];

    // resident B fragments: wave w covers nf0=2w, nf0+1 for all 7 ks
    const bf16x8* wbv = (const bf16x8*)Wb;
    const int nf0 = 2 * w;
    bf16x8 bq[NK][2];
    #pragma unroll
    for (int ks = 0; ks < NK; ++ks)
        #pragma unroll
        for (int nj = 0; nj < 2; ++nj)
            bq[ks][nj] = wbv[(ks * 8 + nf0 + nj) * 64 + l];

    // staging unit map (t-independent): unit u = tid + j*256 in [0,800)
    int rowj[4], c8j[4];
    #pragma unroll
    for (int j = 0; j < 4; ++j) {
        int u = tid + j * 256;
        rowj[j] = u / 25;
        c8j[j]  = u - rowj[j] * 25;
    }
    const bool has3 = (tid < 32);                 // unit 768+tid valid only tid<32

    float4 sreg[4][2];
    auto loadtile = [&](int t) {
        const float* g = x + (row0 + (size_t)t * TROWS) * CBAND;
        #pragma unroll
        for (int j = 0; j < 4; ++j) {
            if (j < 3 || has3) {
                const float4* p = (const float4*)(g + rowj[j] * CBAND + c8j[j] * 8);
                sreg[j][0] = p[0];
                sreg[j][1] = p[1];
            }
        }
    };
    auto writetile = [&](int t) {
        unsigned short* d = xs[t & 1];
        #pragma unroll
        for (int j = 0; j < 4; ++j) {
            if (j < 3 || has3) {
                uint4 pk;
                pk.x = pkbf(sreg[j][0].x, sreg[j][0].y);
                pk.y = pkbf(sreg[j][0].z, sreg[j][0].w);
                pk.z = pkbf(sreg[j][1].x, sreg[j][1].y);
                pk.w = pkbf(sreg[j][1].z, sreg[j][1].w);
                *(uint4*)&d[rowj[j] * XSTR + c8j[j] * 8] = pk;
            }
        }
    };

    const int fr = l & 15;     // fragment row / D col
    const int g4 = l >> 4;     // k subgroup / D row group

    loadtile(0);
    writetile(0);
    loadtile(1);
    __syncthreads();                              // buf0 ready

    for (int t = 0; t < NTILE; ++t) {
        const unsigned short* xb = xs[t & 1];
        f32x4 acc[2][2];
        #pragma unroll
        for (int mi = 0; mi < 2; ++mi)
            #pragma unroll
            for (int nj = 0; nj < 2; ++nj) acc[mi][nj] = (f32x4){0.f, 0.f, 0.f, 0.f};

        #pragma unroll
        for (int ks = 0; ks < NK; ++ks) {
            bf16x8 a0 = *(const bf16x8*)&xb[fr * XSTR + ks * 32 + g4 * 8];
            bf16x8 a1 = *(const bf16x8*)&xb[(fr + 16) * XSTR + ks * 32 + g4 * 8];
            #pragma unroll
            for (int nj = 0; nj < 2; ++nj) {
                acc[0][nj] = __builtin_amdgcn_mfma_f32_16x16x32_bf16(a0, bq[ks][nj], acc[0][nj], 0, 0, 0);
                acc[1][nj] = __builtin_amdgcn_mfma_f32_16x16x32_bf16(a1, bq[ks][nj], acc[1][nj], 0, 0, 0);
            }
        }

        if (w < 2) {
            // h1 waves: partial f-dot with c1, reduce over 16 cols in-wave
            #pragma unroll
            for (int mi = 0; mi < 2; ++mi) {
                #pragma unroll
                for (int r = 0; r < 4; ++r) {
                    float part = 0.f;
                    #pragma unroll
                    for (int nj = 0; nj < 2; ++nj)
                        part += lrelu(acc[mi][nj][r]) * c1s[(nf0 + nj) * 16 + fr];
                    part += __shfl_xor(part, 1);
                    part += __shfl_xor(part, 2);
                    part += __shfl_xor(part, 4);
                    part += __shfl_xor(part, 8);
                    if (fr == 0) hpart[t & 1][w][mi * 16 + g4 * 4 + r] = part;
                }
            }
        } else {
            // h2 waves: store lrelu as bf16, layout h2[b][f][p], 4 p per lane
            #pragma unroll
            for (int mi = 0; mi < 2; ++mi) {
                int p0 = pbase + t * TROWS + mi * 16 + g4 * 4;
                #pragma unroll
                for (int nj = 0; nj < 2; ++nj) {
                    int f = (nf0 + nj - 4) * 16 + fr;
                    uint2 pk;
                    pk.x = pkbf(lrelu(acc[mi][nj][0]), lrelu(acc[mi][nj][1]));
                    pk.y = pkbf(lrelu(acc[mi][nj][2]), lrelu(acc[mi][nj][3]));
                    *(uint2*)&h2[(((size_t)bb * 64 + f) << 10) + p0] = pk;
                }
            }
        }

        if (t + 1 < NTILE) writetile(t + 1);      // regs from loadtile(t+1): landed
        if (t + 2 < NTILE) loadtile(t + 2);       // consumed next iter
        __syncthreads();                          // buf(t+1) ready; hpart[t&1] visible

        if (w == 3 && l < TROWS) {                // combine tile t's h1 partials
            int p = pbase + t * TROWS + l;
            float v = (hpart[t & 1][0][l] + hpart[t & 1][1][l]) * (1.f / 64.f);
            mcT[(size_t)p * BS + bb] = v;
        }
    }
}

// ---------------------------------------------------------------------------
// Kernel 2: softmax over batch per pixel; mcT[p][b] -> attnN[b][p]
// ---------------------------------------------------------------------------
__global__ __launch_bounds__(256) void softmax_b(
    const float* __restrict__ mcT, float* __restrict__ attnN)
{
    int p = blockIdx.x, t = threadIdx.x;
    float v = mcT[(size_t)p * BS + t];
    float m = v;
    #pragma unroll
    for (int o = 32; o > 0; o >>= 1) m = fmaxf(m, __shfl_xor(m, o));
    __shared__ float r1[4], r2[4];
    int w = t >> 6, lz = t & 63;
    if (lz == 0) r1[w] = m;
    __syncthreads();
    m = fmaxf(fmaxf(r1[0], r1[1]), fmaxf(r1[2], r1[3]));
    float e = expf(v - m);
    float s = e;
    #pragma unroll
    for (int o = 32; o > 0; o >>= 1) s += __shfl_xor(s, o);
    if (lz == 0) r2[w] = s;
    __syncthreads();
    s = r2[0] + r2[1] + r2[2] + r2[3];
    attnN[(size_t)t * PIX + p] = e / s;
}

// ---------------------------------------------------------------------------
// Kernel 3: neighbour[b,f] = sum_p h2[b][f][p] * attn[b][p]; blend w/ chalf.
// 1024 threads (16 waves) per block; wave handles 4 f values.
// ---------------------------------------------------------------------------
__global__ __launch_bounds__(1024) void neighbour_k(
    const unsigned short* __restrict__ h2, const float* __restrict__ attnN,
    const float* __restrict__ chalf, float* __restrict__ out)
{
    int b = blockIdx.x, tid = threadIdx.x;
    int l = tid & 63, w = tid >> 6;       // 16 waves
    __shared__ float att[PIX];
    if (tid < PIX) att[tid] = attnN[(size_t)b * PIX + tid];
    __syncthreads();

    float av[16];
    #pragma unroll
    for (int i = 0; i < 8; ++i) av[i]     = att[l * 8 + i];
    #pragma unroll
    for (int i = 0; i < 8; ++i) av[8 + i] = att[512 + l * 8 + i];

    const unsigned short* hb = h2 + ((size_t)b * 64) * 1024;
    #pragma unroll
    for (int j = 0; j < 4; ++j) {
        int f = w * 4 + j;
        const unsigned short* hf = hb + (size_t)f * 1024;
        bf16x8 h0 = *(const bf16x8*)&hf[l * 8];
        bf16x8 h1 = *(const bf16x8*)&hf[512 + l * 8];
        float acc = 0.f;
        #pragma unroll
        for (int i = 0; i < 8; ++i) acc += bf2f(h0[i]) * av[i];
        #pragma unroll
        for (int i = 0; i < 8; ++i) acc += bf2f(h1[i]) * av[8 + i];
        #pragma unroll
        for (int o = 32; o > 0; o >>= 1) acc += __shfl_xor(acc, o);
        if (l == 0)
            out[b * FEAT + f] = chalf[b * FEAT + f] + (1.f - BETA) * acc;
    }
}

// ---------------------------------------------------------------------------
extern "C" void kernel_launch(void* const* d_in, const int* in_sizes, int n_in,
                              void* d_out, int out_size, void* d_ws, size_t ws_size,
                              hipStream_t stream)
{
    const float* x  = (const float*)d_in[0];
    const float* Wk = (const float*)d_in[1];
    const float* Wv = (const float*)d_in[2];
    const float* Wn = (const float*)d_in[3];
    float* out = (float*)d_out;

    float* ws    = (float*)d_ws;
    float* c1    = ws;                                   // 16384 f
    float* chalf = ws + 16384;                           // 16384 f
    float* mcT   = ws + 32768;                           // 262144 f  [p][b]
    float* attnN = ws + 294912;                          // 262144 f  [b][p]
    unsigned short* Wb = (unsigned short*)(ws + 557056); // 28672 u16
    unsigned short* h2 = (unsigned short*)((char*)d_ws + 2285568); // 33.5 MB

    prep_k   <<<270,  256, 0, stream>>>(x, Wk, Wv, Wn, Wb, c1, chalf);
    gemm_mfma<<<2048, 256, 0, stream>>>(x, Wb, c1, mcT, h2);
    softmax_b<<<PIX,  256, 0, stream>>>(mcT, attnN);
    neighbour_k<<<BS, 1024, 0, stream>>>(h2, attnN, chalf, out);
}